// Round 4
// baseline (155.044 us; speedup 1.0000x reference)
//
#include <hip/hip_runtime.h>

typedef unsigned short u16;
typedef unsigned int u32;
using f32x4 = __attribute__((ext_vector_type(4))) float;
using s16x8 = __attribute__((ext_vector_type(8))) short;
using u16x4 = __attribute__((ext_vector_type(4))) unsigned short;
using u16x8 = __attribute__((ext_vector_type(8))) unsigned short;

namespace {

constexpr int T = 1024;
constexpr int C = 512;

__device__ inline u16 f2bf(float f) {
  u32 u = __builtin_bit_cast(u32, f);
  u32 r = (u + 0x7fffu + ((u >> 16) & 1u)) >> 16;
  return (u16)r;
}
__device__ inline float bf2f(u16 v) {
  return __builtin_bit_cast(float, (u32)v << 16);
}
__device__ inline f32x4 mfma16(s16x8 a, s16x8 b, f32x4 c) {
  return __builtin_amdgcn_mfma_f32_16x16x32_bf16(a, b, c, 0, 0, 0);
}

// ---------------------------------------------------------------------------
// fp32 -> bf16 conversion
// ---------------------------------------------------------------------------
__global__ __launch_bounds__(256) void convert_all(
    const float* __restrict__ x, const float* __restrict__ Wq,
    const float* __restrict__ Wk, const float* __restrict__ Wv,
    const float* __restrict__ Wo, u16* __restrict__ xb, u16* __restrict__ Wqb,
    u16* __restrict__ Wkb, u16* __restrict__ Wvb, u16* __restrict__ Wob) {
  const int tid = threadIdx.x;
  const int bid = blockIdx.x;
  const float* src;
  u16* dst;
  size_t off;
  if (bid < 2048) {
    src = x; dst = xb;
    off = ((size_t)bid * 256 + tid) * 4;
  } else {
    const int j = bid - 2048;
    const int w = j >> 8;
    src = w == 0 ? Wq : w == 1 ? Wk : w == 2 ? Wv : Wo;
    dst = w == 0 ? Wqb : w == 1 ? Wkb : w == 2 ? Wvb : Wob;
    off = (((size_t)(j & 255)) * 256 + tid) * 4;
  }
  const float4 v = *reinterpret_cast<const float4*>(src + off);
  u16x4 o;
  o[0] = f2bf(v.x); o[1] = f2bf(v.y); o[2] = f2bf(v.z); o[3] = f2bf(v.w);
  *reinterpret_cast<u16x4*>(dst + off) = o;
}

// ---------------------------------------------------------------------------
// Fused q/k/v projection GEMM (bf16 MFMA).  Y[o][t] = sum_c W[o][c] x[c][t].
// wsel 0(q)/1(k): out [b][h][t][dd] bf16.  wsel 2(v): out [b][h][dd][t] bf16.
// ---------------------------------------------------------------------------
__global__ __launch_bounds__(256) void qkv_gemm(
    const u16* __restrict__ xb, const u16* __restrict__ Wqb,
    const u16* __restrict__ Wkb, const u16* __restrict__ Wvb,
    const float* __restrict__ bq, const float* __restrict__ bk,
    const float* __restrict__ bv, u16* __restrict__ qb, u16* __restrict__ kb,
    u16* __restrict__ vb) {
  __shared__ u16 Bs[2][128 * 32];
  __shared__ float sbias[64];
  const int tid = threadIdx.x;
  const int z = blockIdx.z;
  const int b = z / 3, wsel = z - 3 * b;
  const u16* W = wsel == 0 ? Wqb : wsel == 1 ? Wkb : Wvb;
  const float* bias = wsel == 0 ? bq : wsel == 1 ? bk : bv;
  const int o0 = blockIdx.y * 64;
  const int t0 = blockIdx.x * 128;
  if (tid < 16)
    *reinterpret_cast<float4*>(&sbias[tid * 4]) =
        *reinterpret_cast<const float4*>(&bias[o0 + tid * 4]);

  const int l = tid & 63, wid = tid >> 6;
  const int wm = wid >> 1, wn = wid & 1;
  const int lr = l & 15, lg = l >> 4;

  const int cpair = tid & 15, tgrp = tid >> 4;
  const u16* xrow =
      xb + ((size_t)(b * C) + 2 * cpair) * T + t0 + 8 * tgrp;

  const u16* Arow0 = W + (size_t)(o0 + 32 * wm + lr) * C + 8 * lg;
  const u16* Arow1 = Arow0 + 16 * C;

  f32x4 acc[2][4] = {};

  auto stage = [&](int kk, int buf) {
    const u16* p = xrow + (size_t)kk * 32 * T;
    const u16x8 v0 = *reinterpret_cast<const u16x8*>(p);
    const u16x8 v1 = *reinterpret_cast<const u16x8*>(p + T);
    char* base = (char*)&Bs[buf][0];
#pragma unroll
    for (int j = 0; j < 8; ++j) {
      const int t = 8 * tgrp + j;
      const u32 w2 = (u32)v0[j] | ((u32)v1[j] << 16);
      *(u32*)(base + ((t * 64 + 4 * cpair) ^ ((t & 3) << 4))) = w2;
    }
  };

  s16x8 a0 = *reinterpret_cast<const s16x8*>(Arow0);
  s16x8 a1 = *reinterpret_cast<const s16x8*>(Arow1);
  stage(0, 0);
  __syncthreads();

  for (int kk = 0; kk < 16; ++kk) {
    s16x8 an0, an1;
    if (kk < 15) {
      an0 = *reinterpret_cast<const s16x8*>(Arow0 + (kk + 1) * 32);
      an1 = *reinterpret_cast<const s16x8*>(Arow1 + (kk + 1) * 32);
      stage(kk + 1, (kk + 1) & 1);
    }
    const char* rb = (const char*)&Bs[kk & 1][0];
#pragma unroll
    for (int nf = 0; nf < 4; ++nf) {
      const int t = 64 * wn + 16 * nf + lr;
      const s16x8 bfrag = *reinterpret_cast<const s16x8*>(
          rb + ((t * 64 + 16 * lg) ^ ((t & 3) << 4)));
      acc[0][nf] = mfma16(a0, bfrag, acc[0][nf]);
      acc[1][nf] = mfma16(a1, bfrag, acc[1][nf]);
    }
    __syncthreads();
    if (kk < 15) { a0 = an0; a1 = an1; }
  }

  const int h = o0 >> 6;
  if (wsel < 2) {
    u16* dst = (wsel == 0) ? qb : kb;
#pragma unroll
    for (int m = 0; m < 2; ++m) {
      const int ob = 32 * wm + 16 * m + 4 * lg;
#pragma unroll
      for (int nf = 0; nf < 4; ++nf) {
        const int t = t0 + 64 * wn + 16 * nf + lr;
        u16x4 pk;
#pragma unroll
        for (int r = 0; r < 4; ++r) pk[r] = f2bf(acc[m][nf][r] + sbias[ob + r]);
        *reinterpret_cast<u16x4*>(
            &dst[((size_t)((b * 8 + h) * T) + t) * 64 + ob]) = pk;
      }
    }
  } else {
#pragma unroll
    for (int m = 0; m < 2; ++m) {
      const int ob = 32 * wm + 16 * m + 4 * lg;
#pragma unroll
      for (int nf = 0; nf < 4; ++nf) {
        const int t = t0 + 64 * wn + 16 * nf + lr;
#pragma unroll
        for (int r = 0; r < 4; ++r)
          vb[((size_t)((b * 8 + h) * 64) + ob + r) * T + t] =
              f2bf(acc[m][nf][r] + sbias[ob + r]);
      }
    }
  }
}

// ---------------------------------------------------------------------------
// MFMA flash attention, split-s: each 16-t strip is handled by TWO waves
// (even/odd s-tiles) with private (m,l,O); merged once at the end via LDS.
// Block = (b, h, 32-t chunk), 4 waves; grid 1024 -> 16 waves/CU.
// K frags register-prefetched one tile ahead; V frags issued under softmax.
// q,k: [b][h][t][64] bf16 ; v: [b][h][64][t] bf16 ; out att: [b][h][t][64].
// ---------------------------------------------------------------------------
__global__ __launch_bounds__(256, 4) void attn_mfma(
    const u16* __restrict__ qb, const u16* __restrict__ kb,
    const u16* __restrict__ vb, const int* __restrict__ mask,
    const float* __restrict__ ek, const float* __restrict__ ev,
    u16* __restrict__ attb) {
  __shared__ u16 Qs[32 * 64];       // 32 t-rows (128B each), XOR-swizzled
  __shared__ float Ps[4][16 * 68];  // per-wave P~ fp32; reused as merge buf
  __shared__ float rkk[32][12];
  __shared__ float eks[9][64];
  __shared__ float evs[9][64];
  __shared__ float mlm[4][16][2];   // per-wave (m, l) per strip row
  __shared__ int msk[1024];

  const int b = blockIdx.z, h = blockIdx.y, tc = blockIdx.x * 32;
  const int tid = threadIdx.x;
  const int l = tid & 63, wid = tid >> 6;
  const int lr = l & 15, lg = l >> 4;
  const int sid = wid >> 1;   // strip id (0,1)
  const int par = wid & 1;    // s-tile parity for this wave
  const int tb = tc + 16 * sid;  // strip base (global t)

  const size_t bh = (size_t)(b * 8 + h);
  const u16* qrow = qb + (bh * T + tc) * 64;
  const u16* kbh = kb + bh * T * 64;  // rows s, cols dd
  const u16* vbh = vb + bh * 64 * T;  // rows dd, cols s

  {  // stage Q: 32 rows x 64 dd, swizzled b128 (one shot, 256 threads)
    char* qs = (char*)Qs;
    const int t = tid >> 3, slot = tid & 7;
    const u16x8 v =
        *reinterpret_cast<const u16x8*>(&qrow[(size_t)t * 64 + 8 * slot]);
    *(u16x8*)(qs + ((t * 128 + 16 * slot) ^ ((t & 7) << 4))) = v;
  }
  if (tid < 144) {
    reinterpret_cast<float4*>(&eks[0][0])[tid] =
        reinterpret_cast<const float4*>(ek)[tid];
    reinterpret_cast<float4*>(&evs[0][0])[tid] =
        reinterpret_cast<const float4*>(ev)[tid];
  }
  reinterpret_cast<int4*>(msk)[tid] =
      reinterpret_cast<const int4*>(mask + b * T)[tid];
  __syncthreads();

  {  // rk[t][w] = 0.125 * Q[t].ek[w]  (32 rows x 9 w = 288 tasks)
    const char* qs = (const char*)Qs;
    for (int task = tid; task < 288; task += 256) {
      const int r = task / 9, w = task - 9 * r;
      float s = 0.f;
      const float* er = &eks[w][0];
#pragma unroll 8
      for (int dd = 0; dd < 64; ++dd) {
        const u16 qv = *(const u16*)(qs + ((r * 128 + 2 * dd) ^ ((r & 7) << 4)));
        s += bf2f(qv) * er[dd];
      }
      rkk[r][w] = 0.125f * s;
    }
  }

  float m[4], lsum[4];
  f32x4 Oa[4] = {};
#pragma unroll
  for (int r = 0; r < 4; ++r) { m[r] = -1e30f; lsum[r] = 0.f; }

  // Q A-frags for this wave's strip
  const int tA = 16 * sid + lr;
  s16x8 aq0, aq1;
  {
    const char* qs = (const char*)Qs;
    aq0 = *reinterpret_cast<const s16x8*>(
        qs + ((tA * 128 + 16 * lg) ^ ((tA & 7) << 4)));
    aq1 = *reinterpret_cast<const s16x8*>(
        qs + ((tA * 128 + 16 * (lg + 4)) ^ ((tA & 7) << 4)));
  }
  __syncthreads();  // rkk visible; no barriers inside the main loop

  // K fragment registers: current + prefetched-next
  s16x8 kc[8], kn[8];
  {
    const int s0 = par * 64;
#pragma unroll
    for (int nf = 0; nf < 4; ++nf) {
      const u16* kr = kbh + (size_t)(s0 + 16 * nf + lr) * 64 + 8 * lg;
      kc[nf] = *reinterpret_cast<const s16x8*>(kr);
      kc[nf + 4] = *reinterpret_cast<const s16x8*>(kr + 32);
    }
  }

  for (int st = par; st < 16; st += 2) {
    const int s0 = st * 64;
    const int stn = st + 2;
    if (stn < 16) {  // prefetch next K tile (consumed next iteration)
      const int s0n = stn * 64;
#pragma unroll
      for (int nf = 0; nf < 4; ++nf) {
        const u16* kr = kbh + (size_t)(s0n + 16 * nf + lr) * 64 + 8 * lg;
        kn[nf] = *reinterpret_cast<const s16x8*>(kr);
        kn[nf + 4] = *reinterpret_cast<const s16x8*>(kr + 32);
      }
    }

    // QK^T from prefetched registers
    f32x4 S[4] = {};
#pragma unroll
    for (int nf = 0; nf < 4; ++nf) {
      S[nf] = mfma16(aq0, kc[nf], S[nf]);
      S[nf] = mfma16(aq1, kc[nf + 4], S[nf]);
    }

    // V frags issued now; latency hides under softmax VALU work
    s16x8 bv0[4], bv1[4];
#pragma unroll
    for (int nf = 0; nf < 4; ++nf) {
      const u16* vr = vbh + (size_t)(16 * nf + lr) * T + s0 + 8 * lg;
      bv0[nf] = *reinterpret_cast<const s16x8*>(vr);
      bv1[nf] = *reinterpret_cast<const s16x8*>(vr + 32);
    }

    const bool diag = (s0 <= tb + 19) && (s0 + 63 >= tb - 4);

    // scale + rel-k + mask
#pragma unroll
    for (int nf = 0; nf < 4; ++nf) {
      const int sl_ = 16 * nf + lr;
      const int mz = msk[s0 + sl_];
#pragma unroll
      for (int r = 0; r < 4; ++r) {
        const int tl = 4 * lg + r;  // row within strip
        float v = S[nf][r] * 0.125f;
        if (diag) {
          const int sd = (s0 + sl_) - (tb + tl);
          if (sd >= -4 && sd <= 4) v += rkk[16 * sid + tl][sd + 4];
        }
        S[nf][r] = (mz == 0) ? -10000.0f : v;
      }
    }

    // online softmax (reduce over the 16 lr lanes)
    float pex[4][4], corr[4];
#pragma unroll
    for (int r = 0; r < 4; ++r) {
      float rm = fmaxf(fmaxf(S[0][r], S[1][r]), fmaxf(S[2][r], S[3][r]));
#pragma unroll
      for (int off = 1; off < 16; off <<= 1) rm = fmaxf(rm, __shfl_xor(rm, off));
      const float mn = fmaxf(m[r], rm);
      corr[r] = __expf(m[r] - mn);
      m[r] = mn;
      float rs = 0.f;
#pragma unroll
      for (int nf = 0; nf < 4; ++nf) {
        const float p = __expf(S[nf][r] - mn);
        pex[nf][r] = p;
        rs += p;
      }
#pragma unroll
      for (int off = 1; off < 16; off <<= 1) rs += __shfl_xor(rs, off);
      lsum[r] = lsum[r] * corr[r] + rs;
    }
#pragma unroll
    for (int nf = 0; nf < 4; ++nf) {
      f32x4 o = Oa[nf];
      o[0] *= corr[0]; o[1] *= corr[1]; o[2] *= corr[2]; o[3] *= corr[3];
      Oa[nf] = o;
#pragma unroll
      for (int r = 0; r < 4; ++r)
        Ps[wid][(4 * lg + r) * 68 + 16 * nf + lr] = pex[nf][r];
    }

    // O += P~ V
#pragma unroll
    for (int ks = 0; ks < 2; ++ks) {
      const float* prow = &Ps[wid][lr * 68 + 8 * lg + 32 * ks];
      const float4 p0 = *reinterpret_cast<const float4*>(prow);
      const float4 p1 = *reinterpret_cast<const float4*>(prow + 4);
      s16x8 pa;
      pa[0] = (short)f2bf(p0.x); pa[1] = (short)f2bf(p0.y);
      pa[2] = (short)f2bf(p0.z); pa[3] = (short)f2bf(p0.w);
      pa[4] = (short)f2bf(p1.x); pa[5] = (short)f2bf(p1.y);
      pa[6] = (short)f2bf(p1.z); pa[7] = (short)f2bf(p1.w);
#pragma unroll
      for (int nf = 0; nf < 4; ++nf)
        Oa[nf] = mfma16(pa, ks == 0 ? bv0[nf] : bv1[nf], Oa[nf]);
    }

    // rel-v window: O[t] += sum_w P~[t][t-4+w] * ev[w]
    if (diag) {
#pragma unroll
      for (int r = 0; r < 4; ++r) {
        const int tl = 4 * lg + r;
        const int tg = tb + tl;
#pragma unroll
        for (int w = 0; w < 9; ++w) {
          const int sl_ = tg - 4 + w - s0;
          if (sl_ >= 0 && sl_ < 64) {
            const float p = Ps[wid][tl * 68 + sl_];
#pragma unroll
            for (int nf = 0; nf < 4; ++nf)
              Oa[nf][r] += p * evs[w][16 * nf + lr];
          }
        }
      }
    }

    if (stn < 16) {
#pragma unroll
      for (int i = 0; i < 8; ++i) kc[i] = kn[i];
    }
  }

  // ---- write partials (reuse Ps[wid] as the O-partial buffer) ----
#pragma unroll
  for (int nf = 0; nf < 4; ++nf)
#pragma unroll
    for (int r = 0; r < 4; ++r)
      Ps[wid][(4 * lg + r) * 68 + 16 * nf + lr] = Oa[nf][r];
  if (lr == 0) {
#pragma unroll
    for (int r = 0; r < 4; ++r) {
      mlm[wid][4 * lg + r][0] = m[r];
      mlm[wid][4 * lg + r][1] = lsum[r];
    }
  }
  __syncthreads();

  // ---- merge the two parity waves of this strip; each wave does one
  //      32-col half (par selects the half). lane -> (row=lr, colgrp=lg) ----
  {
    const int w0 = 2 * sid, w1 = 2 * sid + 1;
    const int row = lr;
    const float m0 = mlm[w0][row][0], l0 = mlm[w0][row][1];
    const float m1 = mlm[w1][row][0], l1 = mlm[w1][row][1];
    const float mm = fmaxf(m0, m1);
    const float a0 = __expf(m0 - mm), a1 = __expf(m1 - mm);
    const float linv = 1.0f / (l0 * a0 + l1 * a1);
    const int cb = par * 32 + 8 * lg;
    const float* p0 = &Ps[w0][row * 68 + cb];
    const float* p1 = &Ps[w1][row * 68 + cb];
    u16x8 outv;
#pragma unroll
    for (int half = 0; half < 2; ++half) {
      const float4 o0 = *reinterpret_cast<const float4*>(p0 + 4 * half);
      const float4 o1 = *reinterpret_cast<const float4*>(p1 + 4 * half);
#pragma unroll
      for (int j = 0; j < 4; ++j) {
        const float v0 = (&o0.x)[j], v1 = (&o1.x)[j];
        outv[4 * half + j] = f2bf((v0 * a0 + v1 * a1) * linv);
      }
    }
    *reinterpret_cast<u16x8*>(&attb[(bh * T + tb + row) * 64 + cb]) = outv;
  }
}

// ---------------------------------------------------------------------------
// Output projection: out[b][o][t] = sum_c Wo[o][c] att[b][h(c)][t][dd(c)] + bo
// ---------------------------------------------------------------------------
__global__ __launch_bounds__(256) void out_gemm(
    const u16* __restrict__ Wob, const float* __restrict__ bo,
    const u16* __restrict__ attb, float* __restrict__ out) {
  __shared__ u16 Bs[2][128 * 32];
  __shared__ float sbias[64];
  const int tid = threadIdx.x;
  const int b = blockIdx.z;
  const int o0 = blockIdx.y * 64;
  const int t0 = blockIdx.x * 128;
  if (tid < 16)
    *reinterpret_cast<float4*>(&sbias[tid * 4]) =
        *reinterpret_cast<const float4*>(&bo[o0 + tid * 4]);

  const int l = tid & 63, wid = tid >> 6;
  const int wm = wid >> 1, wn = wid & 1;
  const int lr = l & 15, lg = l >> 4;

  const int slot = tid & 3, trow = tid >> 2;
  const u16* Arow0 = Wob + (size_t)(o0 + 32 * wm + lr) * C + 8 * lg;
  const u16* Arow1 = Arow0 + 16 * C;

  f32x4 acc[2][4] = {};

  auto stage = [&](int kk, int buf) {
    const int c0 = kk * 32;
    const int h = c0 >> 6, dd0 = c0 & 63;
    char* base = (char*)&Bs[buf][0];
#pragma unroll
    for (int rep = 0; rep < 2; ++rep) {
      const int t = rep * 64 + trow;
      const u16x8 v = *reinterpret_cast<const u16x8*>(
          &attb[((size_t)((b * 8 + h) * T) + t0 + t) * 64 + dd0 + 8 * slot]);
      *(u16x8*)(base + ((t * 64 + 16 * slot) ^ ((t & 3) << 4))) = v;
    }
  };

  s16x8 a0 = *reinterpret_cast<const s16x8*>(Arow0);
  s16x8 a1 = *reinterpret_cast<const s16x8*>(Arow1);
  stage(0, 0);
  __syncthreads();

  for (int kk = 0; kk < 16; ++kk) {
    s16x8 an0, an1;
    if (kk < 15) {
      an0 = *reinterpret_cast<const s16x8*>(Arow0 + (kk + 1) * 32);
      an1 = *reinterpret_cast<const s16x8*>(Arow1 + (kk + 1) * 32);
      stage(kk + 1, (kk + 1) & 1);
    }
    const char* rb = (const char*)&Bs[kk & 1][0];
#pragma unroll
    for (int nf = 0; nf < 4; ++nf) {
      const int t = 64 * wn + 16 * nf + lr;
      const s16x8 bfrag = *reinterpret_cast<const s16x8*>(
          rb + ((t * 64 + 16 * lg) ^ ((t & 3) << 4)));
      acc[0][nf] = mfma16(a0, bfrag, acc[0][nf]);
      acc[1][nf] = mfma16(a1, bfrag, acc[1][nf]);
    }
    __syncthreads();
    if (kk < 15) { a0 = an0; a1 = an1; }
  }

#pragma unroll
  for (int m = 0; m < 2; ++m) {
    const int ol = 32 * wm + 16 * m + 4 * lg;
#pragma unroll
    for (int nf = 0; nf < 4; ++nf) {
      const int t = t0 + 64 * wn + 16 * nf + lr;
#pragma unroll
      for (int r = 0; r < 4; ++r)
        out[((size_t)(b * C) + o0 + ol + r) * T + t] =
            acc[m][nf][r] + sbias[ol + r];
    }
  }
}

}  // namespace

extern "C" void kernel_launch(void* const* d_in, const int* in_sizes, int n_in,
                              void* d_out, int out_size, void* d_ws,
                              size_t ws_size, hipStream_t stream) {
  const float* x    = (const float*)d_in[0];
  const int*   mask = (const int*)d_in[1];
  const float* Wq   = (const float*)d_in[2];
  const float* bq   = (const float*)d_in[3];
  const float* Wk   = (const float*)d_in[4];
  const float* bk   = (const float*)d_in[5];
  const float* Wv   = (const float*)d_in[6];
  const float* bv   = (const float*)d_in[7];
  const float* Wo   = (const float*)d_in[8];
  const float* bo   = (const float*)d_in[9];
  const float* ek   = (const float*)d_in[10];
  const float* ev   = (const float*)d_in[11];
  float* out = (float*)d_out;

  char* ws = (char*)d_ws;
  u16* xb   = (u16*)(ws);                    // 4 MB  [B][C][T]
  u16* Wqb  = (u16*)(ws + 4194304);          // 512 KB each
  u16* Wkb  = (u16*)(ws + 4718592);
  u16* Wvb  = (u16*)(ws + 5242880);
  u16* Wob  = (u16*)(ws + 5767168);
  u16* qb   = (u16*)(ws + 6291456);          // 4 MB  [B][H][T][64]
  u16* kb   = (u16*)(ws + 10485760);         // 4 MB  [B][H][T][64]
  u16* vb   = (u16*)(ws + 14680064);         // 4 MB  [B][H][64][T]
  u16* attb = (u16*)(ws + 18874368);         // 4 MB  [B][H][T][64]

  convert_all<<<dim3(3072), dim3(256), 0, stream>>>(x, Wq, Wk, Wv, Wo, xb, Wqb,
                                                    Wkb, Wvb, Wob);
  qkv_gemm<<<dim3(8, 8, 12), dim3(256), 0, stream>>>(xb, Wqb, Wkb, Wvb, bq, bk,
                                                     bv, qb, kb, vb);
  attn_mfma<<<dim3(32, 8, 4), dim3(256), 0, stream>>>(qb, kb, vb, mask, ek, ev,
                                                      attb);
  out_gemm<<<dim3(8, 8, 4), dim3(256), 0, stream>>>(Wob, bo, attb, out);
}

// Round 5
// 116.583 us; speedup vs baseline: 1.3299x; 1.3299x over previous
//
#include <hip/hip_runtime.h>

typedef unsigned short u16;
typedef unsigned int u32;
using f32x4 = __attribute__((ext_vector_type(4))) float;
using s16x8 = __attribute__((ext_vector_type(8))) short;
using u16x4 = __attribute__((ext_vector_type(4))) unsigned short;
using u16x8 = __attribute__((ext_vector_type(8))) unsigned short;

namespace {

constexpr int T = 1024;
constexpr int C = 512;

__device__ inline u16 f2bf(float f) {
  u32 u = __builtin_bit_cast(u32, f);
  u32 r = (u + 0x7fffu + ((u >> 16) & 1u)) >> 16;
  return (u16)r;
}
__device__ inline float bf2f(u16 v) {
  return __builtin_bit_cast(float, (u32)v << 16);
}
__device__ inline f32x4 mfma16(s16x8 a, s16x8 b, f32x4 c) {
  return __builtin_amdgcn_mfma_f32_16x16x32_bf16(a, b, c, 0, 0, 0);
}

// ---------------------------------------------------------------------------
// fp32 -> bf16 conversion
// ---------------------------------------------------------------------------
__global__ __launch_bounds__(256) void convert_all(
    const float* __restrict__ x, const float* __restrict__ Wq,
    const float* __restrict__ Wk, const float* __restrict__ Wv,
    const float* __restrict__ Wo, u16* __restrict__ xb, u16* __restrict__ Wqb,
    u16* __restrict__ Wkb, u16* __restrict__ Wvb, u16* __restrict__ Wob) {
  const int tid = threadIdx.x;
  const int bid = blockIdx.x;
  const float* src;
  u16* dst;
  size_t off;
  if (bid < 2048) {
    src = x; dst = xb;
    off = ((size_t)bid * 256 + tid) * 4;
  } else {
    const int j = bid - 2048;
    const int w = j >> 8;
    src = w == 0 ? Wq : w == 1 ? Wk : w == 2 ? Wv : Wo;
    dst = w == 0 ? Wqb : w == 1 ? Wkb : w == 2 ? Wvb : Wob;
    off = (((size_t)(j & 255)) * 256 + tid) * 4;
  }
  const float4 v = *reinterpret_cast<const float4*>(src + off);
  u16x4 o;
  o[0] = f2bf(v.x); o[1] = f2bf(v.y); o[2] = f2bf(v.z); o[3] = f2bf(v.w);
  *reinterpret_cast<u16x4*>(dst + off) = o;
}

// ---------------------------------------------------------------------------
// Fused q/k/v projection GEMM (bf16 MFMA).  Y[o][t] = sum_c W[o][c] x[c][t].
// wsel 0(q)/1(k): out [b][h][t][dd] bf16.  wsel 2(v): out [b][h][dd][t] bf16.
// ---------------------------------------------------------------------------
__global__ __launch_bounds__(256) void qkv_gemm(
    const u16* __restrict__ xb, const u16* __restrict__ Wqb,
    const u16* __restrict__ Wkb, const u16* __restrict__ Wvb,
    const float* __restrict__ bq, const float* __restrict__ bk,
    const float* __restrict__ bv, u16* __restrict__ qb, u16* __restrict__ kb,
    u16* __restrict__ vb) {
  __shared__ u16 Bs[2][128 * 32];
  __shared__ float sbias[64];
  const int tid = threadIdx.x;
  const int z = blockIdx.z;
  const int b = z / 3, wsel = z - 3 * b;
  const u16* W = wsel == 0 ? Wqb : wsel == 1 ? Wkb : Wvb;
  const float* bias = wsel == 0 ? bq : wsel == 1 ? bk : bv;
  const int o0 = blockIdx.y * 64;
  const int t0 = blockIdx.x * 128;
  if (tid < 16)
    *reinterpret_cast<float4*>(&sbias[tid * 4]) =
        *reinterpret_cast<const float4*>(&bias[o0 + tid * 4]);

  const int l = tid & 63, wid = tid >> 6;
  const int wm = wid >> 1, wn = wid & 1;
  const int lr = l & 15, lg = l >> 4;

  const int cpair = tid & 15, tgrp = tid >> 4;
  const u16* xrow =
      xb + ((size_t)(b * C) + 2 * cpair) * T + t0 + 8 * tgrp;

  const u16* Arow0 = W + (size_t)(o0 + 32 * wm + lr) * C + 8 * lg;
  const u16* Arow1 = Arow0 + 16 * C;

  f32x4 acc[2][4] = {};

  auto stage = [&](int kk, int buf) {
    const u16* p = xrow + (size_t)kk * 32 * T;
    const u16x8 v0 = *reinterpret_cast<const u16x8*>(p);
    const u16x8 v1 = *reinterpret_cast<const u16x8*>(p + T);
    char* base = (char*)&Bs[buf][0];
#pragma unroll
    for (int j = 0; j < 8; ++j) {
      const int t = 8 * tgrp + j;
      const u32 w2 = (u32)v0[j] | ((u32)v1[j] << 16);
      *(u32*)(base + ((t * 64 + 4 * cpair) ^ ((t & 3) << 4))) = w2;
    }
  };

  s16x8 a0 = *reinterpret_cast<const s16x8*>(Arow0);
  s16x8 a1 = *reinterpret_cast<const s16x8*>(Arow1);
  stage(0, 0);
  __syncthreads();

  for (int kk = 0; kk < 16; ++kk) {
    s16x8 an0, an1;
    if (kk < 15) {
      an0 = *reinterpret_cast<const s16x8*>(Arow0 + (kk + 1) * 32);
      an1 = *reinterpret_cast<const s16x8*>(Arow1 + (kk + 1) * 32);
      stage(kk + 1, (kk + 1) & 1);
    }
    const char* rb = (const char*)&Bs[kk & 1][0];
#pragma unroll
    for (int nf = 0; nf < 4; ++nf) {
      const int t = 64 * wn + 16 * nf + lr;
      const s16x8 bfrag = *reinterpret_cast<const s16x8*>(
          rb + ((t * 64 + 16 * lg) ^ ((t & 3) << 4)));
      acc[0][nf] = mfma16(a0, bfrag, acc[0][nf]);
      acc[1][nf] = mfma16(a1, bfrag, acc[1][nf]);
    }
    __syncthreads();
    if (kk < 15) { a0 = an0; a1 = an1; }
  }

  const int h = o0 >> 6;
  if (wsel < 2) {
    u16* dst = (wsel == 0) ? qb : kb;
#pragma unroll
    for (int m = 0; m < 2; ++m) {
      const int ob = 32 * wm + 16 * m + 4 * lg;
#pragma unroll
      for (int nf = 0; nf < 4; ++nf) {
        const int t = t0 + 64 * wn + 16 * nf + lr;
        u16x4 pk;
#pragma unroll
        for (int r = 0; r < 4; ++r) pk[r] = f2bf(acc[m][nf][r] + sbias[ob + r]);
        *reinterpret_cast<u16x4*>(
            &dst[((size_t)((b * 8 + h) * T) + t) * 64 + ob]) = pk;
      }
    }
  } else {
#pragma unroll
    for (int m = 0; m < 2; ++m) {
      const int ob = 32 * wm + 16 * m + 4 * lg;
#pragma unroll
      for (int nf = 0; nf < 4; ++nf) {
        const int t = t0 + 64 * wn + 16 * nf + lr;
#pragma unroll
        for (int r = 0; r < 4; ++r)
          vb[((size_t)((b * 8 + h) * 64) + ob + r) * T + t] =
              f2bf(acc[m][nf][r] + sbias[ob + r]);
      }
    }
  }
}

// ---------------------------------------------------------------------------
// MFMA flash attention, split-KV across blocks (flash-decode style).
// Block = (b, h, 64-t chunk, s-half); each block runs R2's proven inner loop
// over 8 of the 16 s-tiles and writes UNNORMALIZED partial O (bf16) + (m,l).
// Grid 1024 -> 4 blocks/CU (LDS 35 KB) -> 16 waves/CU.
// P-exchange buffer stored as bf16 (direct b128 A-frag); Q staging overlays it.
// ---------------------------------------------------------------------------
__global__ __launch_bounds__(256) void attn_split(
    const u16* __restrict__ qb, const u16* __restrict__ kb,
    const u16* __restrict__ vb, const int* __restrict__ mask,
    const float* __restrict__ ek, const float* __restrict__ ev,
    u16* __restrict__ op0, u16* __restrict__ op1, float2* __restrict__ mlb) {
  __shared__ u16 Ks[64 * 64];       // rows s (128B), XOR-swizzled
  __shared__ u16 Vs[64 * 64];       // rows dd (128B), XOR-swizzled
  __shared__ u16 PsQ[4][16 * 72];   // per-wave P~ bf16 pitch-72; Q overlay
  __shared__ float rkk[64][12];
  __shared__ float eks[9][64];
  __shared__ float evs[9][64];
  __shared__ int msk[512];

  const int z = blockIdx.z;
  const int b = z >> 1, shalf = z & 1;
  const int h = blockIdx.y, tc = blockIdx.x * 64;
  const int tid = threadIdx.x;
  const int l = tid & 63, wid = tid >> 6;
  const int lr = l & 15, lg = l >> 4;
  const int sbase = shalf * 512;

  const size_t bh = (size_t)(b * 8 + h);
  const u16* qrow = qb + (bh * T + tc) * 64;
  const u16* kbh = kb + bh * T * 64;  // rows s, cols dd
  const u16* vbh = vb + bh * 64 * T;  // rows dd, cols s

  {  // stage Q (swizzled b128) into the PsQ overlay (8 KB)
    char* qs = (char*)&PsQ[0][0];
#pragma unroll
    for (int rep = 0; rep < 2; ++rep) {
      const int idx = rep * 256 + tid;
      const int t = idx >> 3, slot = idx & 7;
      const u16x8 v =
          *reinterpret_cast<const u16x8*>(&qrow[(size_t)t * 64 + 8 * slot]);
      *(u16x8*)(qs + ((t * 128 + 16 * slot) ^ ((t & 7) << 4))) = v;
    }
  }
  if (tid < 144) {
    reinterpret_cast<float4*>(&eks[0][0])[tid] =
        reinterpret_cast<const float4*>(ek)[tid];
    reinterpret_cast<float4*>(&evs[0][0])[tid] =
        reinterpret_cast<const float4*>(ev)[tid];
  }
  if (tid < 128)
    reinterpret_cast<int4*>(msk)[tid] =
        reinterpret_cast<const int4*>(mask + b * T + sbase)[tid];
  __syncthreads();

  {  // rk[t][w] = 0.125 * Q[t].ek[w]
    const char* qs = (const char*)&PsQ[0][0];
    for (int task = tid; task < 576; task += 256) {
      const int r = task / 9, w = task - 9 * r;
      float s = 0.f;
      const float* er = &eks[w][0];
#pragma unroll 8
      for (int dd = 0; dd < 64; ++dd) {
        const u16 qv = *(const u16*)(qs + ((r * 128 + 2 * dd) ^ ((r & 7) << 4)));
        s += bf2f(qv) * er[dd];
      }
      rkk[r][w] = 0.125f * s;
    }
  }

  float m[4], lsum[4];
  f32x4 Oa[4] = {};
#pragma unroll
  for (int r = 0; r < 4; ++r) { m[r] = -1e30f; lsum[r] = 0.f; }

  // Q A-frags for this wave's 16-t strip (read before Ps overwrites overlay)
  const int tA = 16 * wid + lr;
  s16x8 aq0, aq1;
  {
    const char* qs = (const char*)&PsQ[0][0];
    aq0 = *reinterpret_cast<const s16x8*>(
        qs + ((tA * 128 + 16 * lg) ^ ((tA & 7) << 4)));
    aq1 = *reinterpret_cast<const s16x8*>(
        qs + ((tA * 128 + 16 * (lg + 4)) ^ ((tA & 7) << 4)));
  }
  __syncthreads();  // rkk + aq done before main loop touches PsQ

  for (int st = shalf * 8; st < shalf * 8 + 8; ++st) {
    const int s0 = st * 64;
    __syncthreads();  // prev-iter Ks/Vs/Ps reads done
    {
      char* ks_ = (char*)Ks;
      char* vs_ = (char*)Vs;
#pragma unroll
      for (int rep = 0; rep < 2; ++rep) {
        const int idx = rep * 256 + tid;
        const int rrow = idx >> 3, slot = idx & 7;
        const u16x8 kv = *reinterpret_cast<const u16x8*>(
            &kbh[(size_t)(s0 + rrow) * 64 + 8 * slot]);
        *(u16x8*)(ks_ + ((rrow * 128 + 16 * slot) ^ ((rrow & 7) << 4))) = kv;
        const u16x8 vv = *reinterpret_cast<const u16x8*>(
            &vbh[(size_t)rrow * T + s0 + 8 * slot]);
        *(u16x8*)(vs_ + ((rrow * 128 + 16 * slot) ^ ((rrow & 7) << 4))) = vv;
      }
    }
    __syncthreads();

    // S = Q K^T
    f32x4 S[4] = {};
    const char* ksb = (const char*)Ks;
#pragma unroll
    for (int nf = 0; nf < 4; ++nf) {
      const int srow = 16 * nf + lr;
      const int swz = (srow & 7) << 4;
      const s16x8 bk0 = *reinterpret_cast<const s16x8*>(
          ksb + ((srow * 128 + 16 * lg) ^ swz));
      S[nf] = mfma16(aq0, bk0, S[nf]);
      const s16x8 bk1 = *reinterpret_cast<const s16x8*>(
          ksb + ((srow * 128 + 16 * (lg + 4)) ^ swz));
      S[nf] = mfma16(aq1, bk1, S[nf]);
    }

    const bool diag = (s0 <= tc + 67) && (s0 + 63 >= tc - 4);

    // scale + rel-k + mask
#pragma unroll
    for (int nf = 0; nf < 4; ++nf) {
      const int sl_ = 16 * nf + lr;
      const int mz = msk[s0 - sbase + sl_];
#pragma unroll
      for (int r = 0; r < 4; ++r) {
        const int tl = 16 * wid + 4 * lg + r;
        float v = S[nf][r] * 0.125f;
        if (diag) {
          const int sd = (s0 + sl_) - (tc + tl);
          if (sd >= -4 && sd <= 4) v += rkk[tl][sd + 4];
        }
        S[nf][r] = (mz == 0) ? -10000.0f : v;
      }
    }

    // online softmax (reduce over the 16 lr lanes)
    float pex[4][4], corr[4];
#pragma unroll
    for (int r = 0; r < 4; ++r) {
      float rm = fmaxf(fmaxf(S[0][r], S[1][r]), fmaxf(S[2][r], S[3][r]));
#pragma unroll
      for (int off = 1; off < 16; off <<= 1) rm = fmaxf(rm, __shfl_xor(rm, off));
      const float mn = fmaxf(m[r], rm);
      corr[r] = __expf(m[r] - mn);
      m[r] = mn;
      float rs = 0.f;
#pragma unroll
      for (int nf = 0; nf < 4; ++nf) {
        const float p = __expf(S[nf][r] - mn);
        pex[nf][r] = p;
        rs += p;
      }
#pragma unroll
      for (int off = 1; off < 16; off <<= 1) rs += __shfl_xor(rs, off);
      lsum[r] = lsum[r] * corr[r] + rs;
    }
#pragma unroll
    for (int nf = 0; nf < 4; ++nf) {
      f32x4 o = Oa[nf];
      o[0] *= corr[0]; o[1] *= corr[1]; o[2] *= corr[2]; o[3] *= corr[3];
      Oa[nf] = o;
#pragma unroll
      for (int r = 0; r < 4; ++r)
        PsQ[wid][(4 * lg + r) * 72 + 16 * nf + lr] = f2bf(pex[nf][r]);
    }

    // O += P~ V  (A-frag: direct b128 read of bf16 Ps row)
    const char* vsb = (const char*)Vs;
#pragma unroll
    for (int ks = 0; ks < 2; ++ks) {
      const s16x8 pa = *reinterpret_cast<const s16x8*>(
          &PsQ[wid][lr * 72 + 8 * lg + 32 * ks]);
#pragma unroll
      for (int nf = 0; nf < 4; ++nf) {
        const int dd = 16 * nf + lr;
        const s16x8 bv_ = *reinterpret_cast<const s16x8*>(
            vsb + ((dd * 128 + 16 * (lg + 4 * ks)) ^ ((dd & 7) << 4)));
        Oa[nf] = mfma16(pa, bv_, Oa[nf]);
      }
    }

    // rel-v window: O[t] += sum_w P~[t][t-4+w] * ev[w]
    if (diag) {
#pragma unroll
      for (int r = 0; r < 4; ++r) {
        const int tl = 16 * wid + 4 * lg + r;
        const int tg = tc + tl;
#pragma unroll
        for (int w = 0; w < 9; ++w) {
          const int sl_ = tg - 4 + w - s0;
          if (sl_ >= 0 && sl_ < 64) {
            const float p = bf2f(PsQ[wid][(4 * lg + r) * 72 + sl_]);
#pragma unroll
            for (int nf = 0; nf < 4; ++nf)
              Oa[nf][r] += p * evs[w][16 * nf + lr];
          }
        }
      }
    }
  }

  // ---- write unnormalized partials + (m,l) ----
  u16* op = shalf ? op1 : op0;
#pragma unroll
  for (int nf = 0; nf < 4; ++nf)
#pragma unroll
    for (int r = 0; r < 4; ++r) {
      const int tl = 16 * wid + 4 * lg + r;
      op[(bh * T + tc + tl) * 64 + 16 * nf + lr] = f2bf(Oa[nf][r]);
    }
  if (lr == 0) {
#pragma unroll
    for (int r = 0; r < 4; ++r) {
      const int tl = 16 * wid + 4 * lg + r;
      float2 v;
      v.x = m[r];
      v.y = lsum[r];
      mlb[(size_t)shalf * 32768 + bh * T + tc + tl] = v;
    }
  }
}

// ---------------------------------------------------------------------------
// Merge the two s-half partials: att = (a0*O0 + a1*O1) / (a0*l0 + a1*l1)
// 16 rows per block, 16 threads per row (u16x4 each).
// ---------------------------------------------------------------------------
__global__ __launch_bounds__(256) void merge_halves(
    const u16* __restrict__ op0, const u16* __restrict__ op1,
    const float2* __restrict__ mlb, u16* __restrict__ attb) {
  const int tid = threadIdx.x;
  const int row = blockIdx.x * 16 + (tid >> 4);
  const int dd = (tid & 15) * 4;
  const float2 ml0 = mlb[row];
  const float2 ml1 = mlb[32768 + row];
  const float mm = fmaxf(ml0.x, ml1.x);
  const float a0 = __expf(ml0.x - mm), a1 = __expf(ml1.x - mm);
  const float inv = 1.0f / (a0 * ml0.y + a1 * ml1.y);
  const u16x4 v0 = *reinterpret_cast<const u16x4*>(&op0[(size_t)row * 64 + dd]);
  const u16x4 v1 = *reinterpret_cast<const u16x4*>(&op1[(size_t)row * 64 + dd]);
  u16x4 o;
#pragma unroll
  for (int j = 0; j < 4; ++j)
    o[j] = f2bf((bf2f(v0[j]) * a0 + bf2f(v1[j]) * a1) * inv);
  *reinterpret_cast<u16x4*>(&attb[(size_t)row * 64 + dd]) = o;
}

// ---------------------------------------------------------------------------
// Output projection: out[b][o][t] = sum_c Wo[o][c] att[b][h(c)][t][dd(c)] + bo
// ---------------------------------------------------------------------------
__global__ __launch_bounds__(256) void out_gemm(
    const u16* __restrict__ Wob, const float* __restrict__ bo,
    const u16* __restrict__ attb, float* __restrict__ out) {
  __shared__ u16 Bs[2][128 * 32];
  __shared__ float sbias[64];
  const int tid = threadIdx.x;
  const int b = blockIdx.z;
  const int o0 = blockIdx.y * 64;
  const int t0 = blockIdx.x * 128;
  if (tid < 16)
    *reinterpret_cast<float4*>(&sbias[tid * 4]) =
        *reinterpret_cast<const float4*>(&bo[o0 + tid * 4]);

  const int l = tid & 63, wid = tid >> 6;
  const int wm = wid >> 1, wn = wid & 1;
  const int lr = l & 15, lg = l >> 4;

  const int slot = tid & 3, trow = tid >> 2;
  const u16* Arow0 = Wob + (size_t)(o0 + 32 * wm + lr) * C + 8 * lg;
  const u16* Arow1 = Arow0 + 16 * C;

  f32x4 acc[2][4] = {};

  auto stage = [&](int kk, int buf) {
    const int c0 = kk * 32;
    const int h = c0 >> 6, dd0 = c0 & 63;
    char* base = (char*)&Bs[buf][0];
#pragma unroll
    for (int rep = 0; rep < 2; ++rep) {
      const int t = rep * 64 + trow;
      const u16x8 v = *reinterpret_cast<const u16x8*>(
          &attb[((size_t)((b * 8 + h) * T) + t0 + t) * 64 + dd0 + 8 * slot]);
      *(u16x8*)(base + ((t * 64 + 16 * slot) ^ ((t & 3) << 4))) = v;
    }
  };

  s16x8 a0 = *reinterpret_cast<const s16x8*>(Arow0);
  s16x8 a1 = *reinterpret_cast<const s16x8*>(Arow1);
  stage(0, 0);
  __syncthreads();

  for (int kk = 0; kk < 16; ++kk) {
    s16x8 an0, an1;
    if (kk < 15) {
      an0 = *reinterpret_cast<const s16x8*>(Arow0 + (kk + 1) * 32);
      an1 = *reinterpret_cast<const s16x8*>(Arow1 + (kk + 1) * 32);
      stage(kk + 1, (kk + 1) & 1);
    }
    const char* rb = (const char*)&Bs[kk & 1][0];
#pragma unroll
    for (int nf = 0; nf < 4; ++nf) {
      const int t = 64 * wn + 16 * nf + lr;
      const s16x8 bfrag = *reinterpret_cast<const s16x8*>(
          rb + ((t * 64 + 16 * lg) ^ ((t & 3) << 4)));
      acc[0][nf] = mfma16(a0, bfrag, acc[0][nf]);
      acc[1][nf] = mfma16(a1, bfrag, acc[1][nf]);
    }
    __syncthreads();
    if (kk < 15) { a0 = an0; a1 = an1; }
  }

#pragma unroll
  for (int m = 0; m < 2; ++m) {
    const int ol = 32 * wm + 16 * m + 4 * lg;
#pragma unroll
    for (int nf = 0; nf < 4; ++nf) {
      const int t = t0 + 64 * wn + 16 * nf + lr;
#pragma unroll
      for (int r = 0; r < 4; ++r)
        out[((size_t)(b * C) + o0 + ol + r) * T + t] =
            acc[m][nf][r] + sbias[ol + r];
    }
  }
}

}  // namespace

extern "C" void kernel_launch(void* const* d_in, const int* in_sizes, int n_in,
                              void* d_out, int out_size, void* d_ws,
                              size_t ws_size, hipStream_t stream) {
  const float* x    = (const float*)d_in[0];
  const int*   mask = (const int*)d_in[1];
  const float* Wq   = (const float*)d_in[2];
  const float* bq   = (const float*)d_in[3];
  const float* Wk   = (const float*)d_in[4];
  const float* bk   = (const float*)d_in[5];
  const float* Wv   = (const float*)d_in[6];
  const float* bv   = (const float*)d_in[7];
  const float* Wo   = (const float*)d_in[8];
  const float* bo   = (const float*)d_in[9];
  const float* ek   = (const float*)d_in[10];
  const float* ev   = (const float*)d_in[11];
  float* out = (float*)d_out;

  char* ws = (char*)d_ws;
  u16* xb   = (u16*)(ws);                    // 4 MB  [B][C][T]; dead after
                                             //        qkv_gemm -> reused as op0
  u16* Wqb  = (u16*)(ws + 4194304);          // 512 KB each
  u16* Wkb  = (u16*)(ws + 4718592);
  u16* Wvb  = (u16*)(ws + 5242880);
  u16* Wob  = (u16*)(ws + 5767168);
  u16* qb   = (u16*)(ws + 6291456);          // 4 MB  [B][H][T][64]
  u16* kb   = (u16*)(ws + 10485760);         // 4 MB  [B][H][T][64]
  u16* vb   = (u16*)(ws + 14680064);         // 4 MB  [B][H][64][T]
  u16* attb = (u16*)(ws + 18874368);         // 4 MB  [B][H][T][64]
  u16* op0  = xb;                            // 4 MB  partial O, s-half 0
  u16* op1  = (u16*)(ws + 23068672);         // 4 MB  partial O, s-half 1
  float2* mlb = (float2*)(ws + 27262976);    // 512 KB [2][B*H*T] (m,l)

  convert_all<<<dim3(3072), dim3(256), 0, stream>>>(x, Wq, Wk, Wv, Wo, xb, Wqb,
                                                    Wkb, Wvb, Wob);
  qkv_gemm<<<dim3(8, 8, 12), dim3(256), 0, stream>>>(xb, Wqb, Wkb, Wvb, bq, bk,
                                                     bv, qb, kb, vb);
  attn_split<<<dim3(16, 8, 8), dim3(256), 0, stream>>>(qb, kb, vb, mask, ek, ev,
                                                       op0, op1, mlb);
  merge_halves<<<dim3(2048), dim3(256), 0, stream>>>(op0, op1, mlb, attb);
  out_gemm<<<dim3(8, 8, 4), dim3(256), 0, stream>>>(Wob, bo, attb, out);
}